// Round 4
// baseline (106.015 us; speedup 1.0000x reference)
//
#include <hip/hip_runtime.h>
#include <stdint.h>

#define B_N 4096
#define T_N 8
#define DIN 4096
#define H2C 512
#define HC 256
#define NWG1 320
#define NWG2 264

typedef __attribute__((ext_vector_type(8))) short bf16x8;
typedef __attribute__((ext_vector_type(4))) float f32x4;

static __device__ __forceinline__ unsigned short f2bf(float f) {
    union { float f; uint32_t u; } v; v.f = f;
    uint32_t u = v.u;
    uint32_t r = (u + 0x7FFFu + ((u >> 16) & 1u)) >> 16;
    return (unsigned short)r;
}

static __device__ __forceinline__ void gl2lds16(const unsigned short* g, unsigned short* l) {
    __builtin_amdgcn_global_load_lds(
        (const __attribute__((address_space(1))) unsigned int*)(g),
        (__attribute__((address_space(3))) unsigned int*)(l), 16, 0, 0);
}

static __device__ __forceinline__ int xcd_remap(int bid, int nwg) {
    int xcd = bid & 7, idx = bid >> 3;
    int q = nwg >> 3, r = nwg & 7;
    return (xcd < r ? xcd * (q + 1) : r * (q + 1) + (xcd - r) * q) + idx;
}

// ================= mega prep: convert-X | transpose W1,W2 | bucket+bias =================
__global__ void k_pre(const float* __restrict__ f0, const float* __restrict__ f1,
                      const float* __restrict__ f2, const float* __restrict__ f3,
                      const float* __restrict__ W1, const float* __restrict__ W2,
                      const int* __restrict__ task_ids,
                      const float* __restrict__ temb, const float* __restrict__ Ww,
                      const float* __restrict__ bw,
                      unsigned short* __restrict__ Xb, unsigned short* __restrict__ W1t,
                      unsigned short* __restrict__ W2t,
                      int* __restrict__ order, int* __restrict__ tiles, int* __restrict__ ntile,
                      int* __restrict__ tiles2, int* __restrict__ ntile2,
                      float* __restrict__ tb) {
    int blk = blockIdx.x, tid = threadIdx.x;
    if (blk < 8192) {
        // ---- X concat + fp32->bf16, ORIGINAL row order ----
        int g = blk * 256 + tid;
        int b = g >> 9, col = (g & 511) * 8;
        int m = col >> 10, d = col & 1023;
        const float* s = (m == 0) ? f0 : (m == 1) ? f1 : (m == 2) ? f2 : f3;
        const float4* sp = (const float4*)(s + (size_t)b * 1024 + d);
        float4 a = sp[0], c = sp[1];
        uint4 w;
        w.x = (uint32_t)f2bf(a.x) | ((uint32_t)f2bf(a.y) << 16);
        w.y = (uint32_t)f2bf(a.z) | ((uint32_t)f2bf(a.w) << 16);
        w.z = (uint32_t)f2bf(c.x) | ((uint32_t)f2bf(c.y) << 16);
        w.w = (uint32_t)f2bf(c.z) | ((uint32_t)f2bf(c.w) << 16);
        *(uint4*)(Xb + (size_t)b * DIN + col) = w;
        return;
    }
    if (blk < 12544) {
        // ---- weight transpose [T][R][C] fp32 -> [T][C][R] bf16, 64x64 tiles ----
        __shared__ float tile[64][65];
        const float* ip; unsigned short* op; int R, C, bx, by, t;
        if (blk < 12288) {
            int idx = blk - 8192; bx = idx & 63; by = (idx >> 6) & 7; t = idx >> 9;
            R = DIN; C = H2C;
            ip = W1 + (size_t)t * R * C; op = W1t + (size_t)t * R * C;
        } else {
            int idx = blk - 12288; bx = idx & 7; by = (idx >> 3) & 3; t = idx >> 5;
            R = H2C; C = HC;
            ip = W2 + (size_t)t * R * C; op = W2t + (size_t)t * R * C;
        }
        int r0 = bx * 64, c0 = by * 64;
        int lr = tid >> 4, lc4 = (tid & 15) * 4;
        #pragma unroll
        for (int i = 0; i < 4; ++i) {
            float4 v = *(const float4*)&ip[(size_t)(r0 + lr + i * 16) * C + c0 + lc4];
            tile[lr + i * 16][lc4 + 0] = v.x;
            tile[lr + i * 16][lc4 + 1] = v.y;
            tile[lr + i * 16][lc4 + 2] = v.z;
            tile[lr + i * 16][lc4 + 3] = v.w;
        }
        __syncthreads();
        int r4 = (tid & 15) * 4;
        #pragma unroll
        for (int i = 0; i < 4; ++i) {
            int cc = i * 16 + (tid >> 4);
            uint2 wv;
            wv.x = (uint32_t)f2bf(tile[r4 + 0][cc]) | ((uint32_t)f2bf(tile[r4 + 1][cc]) << 16);
            wv.y = (uint32_t)f2bf(tile[r4 + 2][cc]) | ((uint32_t)f2bf(tile[r4 + 3][cc]) << 16);
            *(uint2*)&op[(size_t)(c0 + cc) * R + r0 + r4] = wv;
        }
        return;
    }
    // ---- prep (single block) ----
    __shared__ int lc[T_N], lseg[T_N], lcur[T_N];
    if (tid < T_N) lc[tid] = 0;
    __syncthreads();
    int myt[16];
    #pragma unroll
    for (int i = 0; i < 16; ++i) {
        myt[i] = task_ids[tid * 16 + i];
        atomicAdd(&lc[myt[i]], 1);
    }
    __syncthreads();
    if (tid == 0) {
        int s = 0;
        for (int t = 0; t < T_N; ++t) { lseg[t] = s; lcur[t] = s; s += lc[t]; }
        int n = 0;
        for (int t = 0; t < T_N; ++t)
            for (int r0 = 0; r0 < lc[t]; r0 += 128) {
                tiles[3 * n] = t; tiles[3 * n + 1] = lseg[t] + r0;
                tiles[3 * n + 2] = lc[t] - r0 < 128 ? lc[t] - r0 : 128; ++n;
            }
        ntile[0] = n;
        n = 0;
        for (int t = 0; t < T_N; ++t)
            for (int r0 = 0; r0 < lc[t]; r0 += 16) {
                tiles2[3 * n] = t; tiles2[3 * n + 1] = lseg[t] + r0;
                tiles2[3 * n + 2] = lc[t] - r0 < 16 ? lc[t] - r0 : 16; ++n;
            }
        ntile2[0] = n;
    }
    __syncthreads();
    #pragma unroll
    for (int i = 0; i < 16; ++i) {
        int p = atomicAdd(&lcur[myt[i]], 1);
        order[p] = tid * 16 + i;
    }
    // per-task bias: bw + task_emb @ Ww[256:512]
    int w = tid >> 6, lane = tid & 63;
    for (int t = w; t < T_N; t += 4) {
        int m = lane & 3, hb = (lane >> 2) * 16;
        float s = 0.f;
        for (int h = 0; h < 16; ++h)
            s += temb[t * HC + hb + h] * Ww[((size_t)t * H2C + HC + hb + h) * 4 + m];
        for (int o = 4; o < 64; o <<= 1) s += __shfl_xor(s, o);
        if (lane < 4) tb[t * 4 + lane] = s + bw[t * 4 + lane];
    }
}

// ================= GEMM1: 128x128, split-K=2, COLT=4, A gathered via order =================
__launch_bounds__(256)
__global__ void k_gemm1(const unsigned short* __restrict__ A, const unsigned short* __restrict__ Bt,
                        float* __restrict__ C, const int* __restrict__ order,
                        const int* __restrict__ tiles, const int* __restrict__ ntile) {
    int id = xcd_remap(blockIdx.x, NWG1);
    int tix = id >> 3;
    if (tix >= ntile[0]) return;
    int ct = (id >> 1) & 3, kc = id & 1;
    int t = tiles[3 * tix], prow = tiles[3 * tix + 1], rows = tiles[3 * tix + 2];
    int kb = kc * 2048;

    __shared__ unsigned short lds[2][256 * 64];   // 64 KB

    int tid = threadIdx.x, lane = tid & 63, w = tid >> 6;
    int wm = w >> 1, wn = w & 1;

    const unsigned short* pA[4];
    const unsigned short* pB[4];
    #pragma unroll
    for (int j = 0; j < 4; ++j) {
        int row = j * 32 + (tid >> 3);
        int colg = (tid & 7) ^ (row & 7);
        int rl = row < rows ? row : rows - 1;
        pA[j] = A + (size_t)order[prow + rl] * DIN + kb + colg * 8;
        pB[j] = Bt + ((size_t)t * H2C + ct * 128 + row) * DIN + kb + colg * 8;
    }

    f32x4 acc[4][4];
    #pragma unroll
    for (int m = 0; m < 4; ++m)
        #pragma unroll
        for (int n = 0; n < 4; ++n)
            acc[m][n] = (f32x4){0.f, 0.f, 0.f, 0.f};

    auto stage = [&](int buf, int k0) {
        unsigned short* dA = &lds[buf][w * 512];
        unsigned short* dB = dA + 8192;
        #pragma unroll
        for (int j = 0; j < 4; ++j) gl2lds16(pA[j] + k0, dA + j * 2048);
        #pragma unroll
        for (int j = 0; j < 4; ++j) gl2lds16(pB[j] + k0, dB + j * 2048);
    };

    stage(0, 0);
    __syncthreads();
    int cur = 0;
    for (int it = 0; it < 32; ++it) {
        if (it + 1 < 32) stage(cur ^ 1, (it + 1) * 64);
        const unsigned short* As = &lds[cur][0];
        const unsigned short* Bs = As + 8192;
        #pragma unroll
        for (int ks = 0; ks < 2; ++ks) {
            int g = ks * 4 + (lane >> 4);
            bf16x8 af[4], bfv[4];
            #pragma unroll
            for (int m = 0; m < 4; ++m) {
                int row = wm * 64 + m * 16 + (lane & 15);
                af[m] = *(const bf16x8*)&As[row * 64 + ((g ^ (row & 7)) * 8)];
            }
            #pragma unroll
            for (int n = 0; n < 4; ++n) {
                int row = wn * 64 + n * 16 + (lane & 15);
                bfv[n] = *(const bf16x8*)&Bs[row * 64 + ((g ^ (row & 7)) * 8)];
            }
            #pragma unroll
            for (int m = 0; m < 4; ++m)
                #pragma unroll
                for (int n = 0; n < 4; ++n)
                    acc[m][n] = __builtin_amdgcn_mfma_f32_16x16x32_bf16(af[m], bfv[n], acc[m][n], 0, 0, 0);
        }
        __syncthreads();
        cur ^= 1;
    }

    float* Cb = C + (size_t)kc * B_N * H2C;
    #pragma unroll
    for (int m = 0; m < 4; ++m) {
        #pragma unroll
        for (int n = 0; n < 4; ++n) {
            int col = ct * 128 + wn * 64 + n * 16 + (lane & 15);
            #pragma unroll
            for (int j = 0; j < 4; ++j) {
                int row = wm * 64 + m * 16 + (lane >> 4) * 4 + j;
                if (row < rows)
                    Cb[(size_t)(prow + row) * H2C + col] = acc[m][n][j];
            }
        }
    }
}

// ================= GEMM2 fused: LN1+ReLU -> GEMM(512->256) -> LN2+ReLU -> wdot+softmax =================
__launch_bounds__(256)
__global__ void k_gemm2f(const float* __restrict__ h1p, const unsigned short* __restrict__ W2t,
                         const float* __restrict__ b1, const float* __restrict__ g1,
                         const float* __restrict__ be1,
                         const float* __restrict__ b2, const float* __restrict__ g2,
                         const float* __restrict__ be2,
                         const float* __restrict__ Ww, const float* __restrict__ tb,
                         const int* __restrict__ order,
                         const int* __restrict__ tiles2, const int* __restrict__ ntile2,
                         float* __restrict__ out) {
    __shared__ unsigned short Asm[16 * 512];      // 16 KB, swizzled bf16
    __shared__ unsigned short Bsm[2][256 * 32];   // 2 x 16 KB
    __shared__ float red[16][4][4];

    int id = xcd_remap(blockIdx.x, NWG2);
    if (id >= ntile2[0]) return;
    int t = tiles2[3 * id], prow = tiles2[3 * id + 1], rows = tiles2[3 * id + 2];
    int tid = threadIdx.x, lane = tid & 63, w = tid >> 6;

    // ---- prologue: LN1(sum split-K partials + b1) + ReLU -> bf16 -> Asm ----
    {
        int r = tid >> 4;
        int rl = r < rows ? r : rows - 1;
        int c0 = (tid & 15) * 32;
        const float* p0 = h1p + (size_t)(prow + rl) * H2C + c0;
        const float* p1 = p0 + (size_t)B_N * H2C;
        const float* pb = b1 + t * H2C + c0;
        float x[32];
        float s = 0.f, sq = 0.f;
        #pragma unroll
        for (int i = 0; i < 32; i += 4) {
            float4 a = *(const float4*)(p0 + i);
            float4 b = *(const float4*)(p1 + i);
            float4 c = *(const float4*)(pb + i);
            x[i + 0] = a.x + b.x + c.x; x[i + 1] = a.y + b.y + c.y;
            x[i + 2] = a.z + b.z + c.z; x[i + 3] = a.w + b.w + c.w;
            s += x[i] + x[i + 1] + x[i + 2] + x[i + 3];
            sq += x[i] * x[i] + x[i + 1] * x[i + 1] + x[i + 2] * x[i + 2] + x[i + 3] * x[i + 3];
        }
        #pragma unroll
        for (int o = 1; o < 16; o <<= 1) { s += __shfl_xor(s, o); sq += __shfl_xor(sq, o); }
        float mean = s * (1.f / H2C);
        float var = sq * (1.f / H2C) - mean * mean;
        float rstd = rsqrtf(var + 1e-5f);
        const float* pg = g1 + t * H2C + c0;
        const float* pe = be1 + t * H2C + c0;
        #pragma unroll
        for (int i = 0; i < 32; i += 8) {
            unsigned short y[8];
            #pragma unroll
            for (int q = 0; q < 8; q += 4) {
                float4 gv = *(const float4*)(pg + i + q);
                float4 ev = *(const float4*)(pe + i + q);
                y[q + 0] = f2bf(fmaxf((x[i + q + 0] - mean) * rstd * gv.x + ev.x, 0.f));
                y[q + 1] = f2bf(fmaxf((x[i + q + 1] - mean) * rstd * gv.y + ev.y, 0.f));
                y[q + 2] = f2bf(fmaxf((x[i + q + 2] - mean) * rstd * gv.z + ev.z, 0.f));
                y[q + 3] = f2bf(fmaxf((x[i + q + 3] - mean) * rstd * gv.w + ev.w, 0.f));
            }
            uint4 wv;
            wv.x = (uint32_t)y[0] | ((uint32_t)y[1] << 16);
            wv.y = (uint32_t)y[2] | ((uint32_t)y[3] << 16);
            wv.z = (uint32_t)y[4] | ((uint32_t)y[5] << 16);
            wv.w = (uint32_t)y[6] | ((uint32_t)y[7] << 16);
            int g = (c0 + i) >> 3;
            *(uint4*)&Asm[r * 512 + ((g ^ (r & 7)) * 8)] = wv;
        }
    }

    auto stageB = [&](int buf, int it) {
        #pragma unroll
        for (int j = 0; j < 4; ++j) {
            int G = j * 256 + tid;
            int row = G >> 2, g = G & 3;
            int colg = g ^ (row & 3);
            gl2lds16(W2t + ((size_t)t * HC + row) * H2C + it * 32 + colg * 8,
                     &Bsm[buf][(j * 256 + w * 64) * 8]);
        }
    };

    stageB(0, 0);
    __syncthreads();

    f32x4 acc[4];
    #pragma unroll
    for (int n = 0; n < 4; ++n) acc[n] = (f32x4){0.f, 0.f, 0.f, 0.f};

    for (int it = 0; it < 16; ++it) {
        if (it + 1 < 16) stageB((it + 1) & 1, it + 1);
        const unsigned short* Bs = &Bsm[it & 1][0];
        int g = lane >> 4;
        int arow = lane & 15;
        bf16x8 af = *(const bf16x8*)&Asm[arow * 512 + (((it * 4 + g) ^ (arow & 7)) * 8)];
        #pragma unroll
        for (int n = 0; n < 4; ++n) {
            int brow = w * 64 + n * 16 + arow;
            bf16x8 bv = *(const bf16x8*)&Bs[brow * 32 + ((g ^ (brow & 3)) * 8)];
            acc[n] = __builtin_amdgcn_mfma_f32_16x16x32_bf16(af, bv, acc[n], 0, 0, 0);
        }
        __syncthreads();
    }

    // ---- epilogue: LN2 + ReLU + weight-net dot + softmax + scatter ----
    float b2v[4], g2v[4], e2v[4];
    float4 wv[4];
    #pragma unroll
    for (int n = 0; n < 4; ++n) {
        int col = w * 64 + n * 16 + (lane & 15);
        b2v[n] = b2[t * HC + col];
        g2v[n] = g2[t * HC + col];
        e2v[n] = be2[t * HC + col];
        wv[n] = *(const float4*)&Ww[((size_t)t * H2C + col) * 4];
    }
    float s4[4], q4[4];
    #pragma unroll
    for (int j = 0; j < 4; ++j) {
        float s = 0.f, sq = 0.f;
        #pragma unroll
        for (int n = 0; n < 4; ++n) {
            float xv = acc[n][j] + b2v[n];
            s += xv; sq += xv * xv;
        }
        #pragma unroll
        for (int o = 1; o < 16; o <<= 1) { s += __shfl_xor(s, o); sq += __shfl_xor(sq, o); }
        s4[j] = s; q4[j] = sq;
    }
    if ((lane & 15) == 0) {
        #pragma unroll
        for (int j = 0; j < 4; ++j) {
            int r = (lane >> 4) * 4 + j;
            red[r][w][0] = s4[j];
            red[r][w][1] = q4[j];
        }
    }
    __syncthreads();
    float mean[4], rstd[4];
    #pragma unroll
    for (int j = 0; j < 4; ++j) {
        int r = (lane >> 4) * 4 + j;
        float S = red[r][0][0] + red[r][1][0] + red[r][2][0] + red[r][3][0];
        float SQ = red[r][0][1] + red[r][1][1] + red[r][2][1] + red[r][3][1];
        mean[j] = S * (1.f / HC);
        float var = SQ * (1.f / HC) - mean[j] * mean[j];
        rstd[j] = rsqrtf(var + 1e-5f);
    }
    float p[4][4];
    #pragma unroll
    for (int j = 0; j < 4; ++j) {
        p[j][0] = 0.f; p[j][1] = 0.f; p[j][2] = 0.f; p[j][3] = 0.f;
        #pragma unroll
        for (int n = 0; n < 4; ++n) {
            float yv = fmaxf((acc[n][j] + b2v[n] - mean[j]) * rstd[j] * g2v[n] + e2v[n], 0.f);
            p[j][0] += yv * wv[n].x; p[j][1] += yv * wv[n].y;
            p[j][2] += yv * wv[n].z; p[j][3] += yv * wv[n].w;
        }
        #pragma unroll
        for (int m = 0; m < 4; ++m)
            #pragma unroll
            for (int o = 1; o < 16; o <<= 1) p[j][m] += __shfl_xor(p[j][m], o);
    }
    __syncthreads();
    if ((lane & 15) == 0) {
        #pragma unroll
        for (int j = 0; j < 4; ++j) {
            int r = (lane >> 4) * 4 + j;
            red[r][w][0] = p[j][0]; red[r][w][1] = p[j][1];
            red[r][w][2] = p[j][2]; red[r][w][3] = p[j][3];
        }
    }
    __syncthreads();
    if (tid < 16 && tid < rows) {
        float raw[4];
        #pragma unroll
        for (int m = 0; m < 4; ++m)
            raw[m] = red[tid][0][m] + red[tid][1][m] + red[tid][2][m] + red[tid][3][m] + tb[t * 4 + m];
        float mx = fmaxf(fmaxf(raw[0], raw[1]), fmaxf(raw[2], raw[3]));
        float e0 = expf(raw[0] - mx), e1 = expf(raw[1] - mx);
        float e2 = expf(raw[2] - mx), e3 = expf(raw[3] - mx);
        float si = 1.f / (e0 + e1 + e2 + e3);
        *(float4*)(out + (size_t)order[prow + tid] * 4) = make_float4(e0 * si, e1 * si, e2 * si, e3 * si);
    }
}

extern "C" void kernel_launch(void* const* d_in, const int* in_sizes, int n_in,
                              void* d_out, int out_size, void* d_ws, size_t ws_size,
                              hipStream_t stream) {
    const float* f0 = (const float*)d_in[0];
    const float* f1 = (const float*)d_in[1];
    const float* f2 = (const float*)d_in[2];
    const float* f3 = (const float*)d_in[3];
    const float* W1 = (const float*)d_in[4];
    const float* b1 = (const float*)d_in[5];
    const float* g1 = (const float*)d_in[6];
    const float* be1 = (const float*)d_in[7];
    const float* W2 = (const float*)d_in[8];
    const float* b2 = (const float*)d_in[9];
    const float* g2 = (const float*)d_in[10];
    const float* be2 = (const float*)d_in[11];
    const float* temb = (const float*)d_in[12];
    const float* Ww = (const float*)d_in[13];
    const float* bw = (const float*)d_in[14];
    const int* task_ids = (const int*)d_in[15];
    float* out = (float*)d_out;

    char* ws = (char*)d_ws;
    size_t off = 0;
    auto walloc = [&](size_t bytes) -> void* {
        void* p = ws + off;
        off = (off + bytes + 255) & ~(size_t)255;
        return p;
    };
    float* tb = (float*)walloc(128);
    int* tiles = (int*)walloc(40 * 3 * 4);
    int* ntile = (int*)walloc(4);
    int* tiles2 = (int*)walloc(NWG2 * 3 * 4);
    int* ntile2 = (int*)walloc(4);
    int* order = (int*)walloc((size_t)B_N * 4);
    unsigned short* Xb = (unsigned short*)walloc((size_t)B_N * DIN * 2);
    unsigned short* W1t = (unsigned short*)walloc((size_t)T_N * H2C * DIN * 2);
    unsigned short* W2t = (unsigned short*)walloc((size_t)T_N * HC * H2C * 2);
    float* h1p = (float*)walloc((size_t)2 * B_N * H2C * 4);

    k_pre<<<12545, 256, 0, stream>>>(f0, f1, f2, f3, W1, W2, task_ids, temb, Ww, bw,
                                     Xb, W1t, W2t, order, tiles, ntile, tiles2, ntile2, tb);
    k_gemm1<<<NWG1, 256, 0, stream>>>(Xb, W1t, h1p, order, tiles, ntile);
    k_gemm2f<<<NWG2, 256, 0, stream>>>(h1p, W2t, b1, g1, be1, b2, g2, be2, Ww, tb,
                                       order, tiles2, ntile2, out);
}